// Round 11
// baseline (79.042 us; speedup 1.0000x reference)
//
#include <hip/hip_runtime.h>
#include <math.h>

// Problem dims (fixed by setup_inputs)
constexpr int B = 8;
constexpr int A = 49104;
constexpr int C = 80;       // classes
constexpr int M = 32;       // max annotations
constexpr int TILE = 256;   // anchors per block == threads per block
constexpr int NTILES = (A + TILE - 1) / TILE;  // 192
constexpr int QPA = C / 4;  // 20 float4 per anchor

#define SBAR() __builtin_amdgcn_sched_barrier(0)

// ws layout (floats): [0..7]=cls_sum (log2 units), [8..15]=reg_sum, [16..23]=npos
__global__ void init_ws_kernel(float* ws) {
    int t = threadIdx.x;
    if (t < 24) ws[t] = 0.0f;
}

// Unweighted focal "else" term: f(p) = p^2 * (-log2(1-p)), med3-clamped.
__device__ __forceinline__ void fquad(const float4 p4, float& a0, float& a1) {
    const float px = __builtin_amdgcn_fmed3f(p4.x, 1e-4f, 1.0f - 1e-4f);
    const float py = __builtin_amdgcn_fmed3f(p4.y, 1e-4f, 1.0f - 1e-4f);
    const float pz = __builtin_amdgcn_fmed3f(p4.z, 1e-4f, 1.0f - 1e-4f);
    const float pw = __builtin_amdgcn_fmed3f(p4.w, 1e-4f, 1.0f - 1e-4f);
    a0 = fmaf(px * px, -__log2f(1.0f - px), a0);
    a1 = fmaf(py * py, -__log2f(1.0f - py), a1);
    a0 = fmaf(pz * pz, -__log2f(1.0f - pz), a0);
    a1 = fmaf(pw * pw, -__log2f(1.0f - pw), a1);
}

__global__ __launch_bounds__(TILE, 8) void focal_main_kernel(
    const float* __restrict__ cls,      // (B, A, C)
    const float* __restrict__ reg,      // (B, A, 4)
    const float* __restrict__ anchors,  // (A, 4)  y1,x1,y2,x2
    const float* __restrict__ ann,      // (B, M, 5) x1,y1,x2,y2,label
    float* __restrict__ ws)
{
    __shared__ float s_bx1[M], s_by1[M], s_bx2[M], s_by2[M], s_area[M], s_lab[M];
    __shared__ float s_red[3][4];

    const int t    = threadIdx.x;
    const int tile = blockIdx.x;
    const int b    = blockIdx.y;
    const int base = tile * TILE;
    const int nA   = min(TILE, A - base);

    // Preprocess annotations: invalid boxes become degenerate (zero overlap,
    // +inf area) so the IoU loop needs no validity test.
    if (t < M) {
        const float x1 = ann[(b * M + t) * 5 + 0];
        const float y1 = ann[(b * M + t) * 5 + 1];
        const float x2 = ann[(b * M + t) * 5 + 2];
        const float y2 = ann[(b * M + t) * 5 + 3];
        const float lb = ann[(b * M + t) * 5 + 4];
        const bool v = (lb != -1.0f);
        s_bx1[t]  = v ? x1 :  3e18f;
        s_by1[t]  = v ? y1 :  3e18f;
        s_bx2[t]  = v ? x2 : -3e18f;
        s_by2[t]  = v ? y2 : -3e18f;
        s_area[t] = v ? (x2 - x1) * (y2 - y1) : __builtin_inff();
        s_lab[t]  = lb;
    }

    const float4 an = ((const float4*)anchors)[min(base + t, A - 1)];  // y1,x1,y2,x2
    __syncthreads();

    // --- Issue Phase-B group 0 (8 loads) NOW; sched_barrier pins them here
    // so Phase A's ~600-cycle IoU loop hides their latency. (R9 post-mortem:
    // without the fence the compiler sinks loads to their uses; VGPR=40
    // proved the source pipeline was collapsed.)
    const float4* cp = (const float4*)(cls + ((size_t)b * A + base) * C);
    const bool full = (nA == TILE);
    float4 q0, q1, q2, q3, q4, q5, q6, q7;
    if (full) {
        q0 = cp[t + 0 * TILE]; q1 = cp[t + 1 * TILE];
        q2 = cp[t + 2 * TILE]; q3 = cp[t + 3 * TILE];
        q4 = cp[t + 4 * TILE]; q5 = cp[t + 5 * TILE];
        q6 = cp[t + 6 * TILE]; q7 = cp[t + 7 * TILE];
    }
    SBAR();

    // --- Phase A: division-free band classification.
    const float aw  = an.w - an.y;
    const float ah  = an.z - an.x;
    const float aarea = ah * aw;
    float e4 = -1.0f, e5 = -1.0f;   // max_j (inter - thr*ua); <0 => iou_max < thr
    if (t < nA) {
        #pragma unroll
        for (int j = 0; j < M; ++j) {
            float iw = fmaxf(fminf(an.w, s_bx2[j]) - fmaxf(an.y, s_bx1[j]), 0.0f);
            float ih = fmaxf(fminf(an.z, s_by2[j]) - fmaxf(an.x, s_by1[j]), 0.0f);
            const float inter = iw * ih;
            const float ua = aarea + s_area[j] - inter;   // >=256, clamp never binds
            e4 = fmaxf(e4, fmaf(-0.4f, ua, inter));
            e5 = fmaxf(e5, fmaf(-0.5f, ua, inter));
        }
    }
    const bool pos = (t < nA) && (e5 >= 0.0f);
    const bool ign = (t < nA) && (e4 >= 0.0f) && !pos;   // 0.4 <= iou_max < 0.5

    // --- Rare pos re-pass: precise argmax + label correction + smooth-L1.
    float cls_corr = 0.0f, reg_part = 0.0f, npos_part = 0.0f;
    if (pos) {
        npos_part = 1.0f;
        float best = -2.0f; int arg = 0;
        for (int j = 0; j < M; ++j) {
            float iw = fmaxf(fminf(an.w, s_bx2[j]) - fmaxf(an.y, s_bx1[j]), 0.0f);
            float ih = fmaxf(fminf(an.z, s_by2[j]) - fmaxf(an.x, s_by1[j]), 0.0f);
            const float inter = iw * ih;
            const float ua = fmaxf(aarea + s_area[j] - inter, 1e-8f);
            const float iou = inter / ua;                 // invalid j: 0/inf = 0
            if (iou > best) { best = iou; arg = j; }
        }
        const int lab = (int)s_lab[arg];
        const float pl = fminf(fmaxf(cls[((size_t)b * A + base + t) * C + lab], 1e-4f), 1.0f - 1e-4f);
        const float ql = 1.0f - pl;
        cls_corr = -0.25f * ql * ql * __log2f(pl) + 0.75f * pl * pl * __log2f(ql);

        const float4 r = ((const float4*)reg)[(size_t)b * A + base + t];
        const float gx1 = s_bx1[arg], gy1 = s_by1[arg];
        const float gx2 = s_bx2[arg], gy2 = s_by2[arg];
        float gw = gx2 - gx1;
        float gh = gy2 - gy1;
        const float gcx = gx1 + 0.5f * gw;
        const float gcy = gy1 + 0.5f * gh;
        const float acx = an.y + 0.5f * aw;
        const float acy = an.x + 0.5f * ah;
        gw = fmaxf(gw, 1.0f);
        gh = fmaxf(gh, 1.0f);
        const float t0 = (gcy - acy) / ah;
        const float t1 = (gcx - acx) / aw;
        const float t2 = __logf(gh / ah);
        const float t3 = __logf(gw / aw);
        const float d0 = fabsf(t0 - r.x);
        const float d1 = fabsf(t1 - r.y);
        const float d2 = fabsf(t2 - r.z);
        const float d3 = fabsf(t3 - r.w);
        const float TH = 1.0f / 9.0f;
        const float SH = 0.5f / 9.0f;
        reg_part = ((d0 <= TH) ? 4.5f * d0 * d0 : d0 - SH)
                 + ((d1 <= TH) ? 4.5f * d1 * d1 : d1 - SH)
                 + ((d2 <= TH) ? 4.5f * d2 * d2 : d2 - SH)
                 + ((d3 <= TH) ? 4.5f * d3 * d3 : d3 - SH);
    }

    // --- Phase B: unconditional focal stream, 8-deep batched loads with
    // sched_barrier fences (issue batch -> fence -> consume).
    float accA = 0.0f, accB = 0.0f;
    if (full) {
        // consume G0 (issued before Phase A)
        fquad(q0, accA, accB); fquad(q1, accA, accB);
        fquad(q2, accA, accB); fquad(q3, accA, accB);
        fquad(q4, accA, accB); fquad(q5, accA, accB);
        fquad(q6, accA, accB); fquad(q7, accA, accB);
        // issue G1
        q0 = cp[t +  8 * TILE]; q1 = cp[t +  9 * TILE];
        q2 = cp[t + 10 * TILE]; q3 = cp[t + 11 * TILE];
        q4 = cp[t + 12 * TILE]; q5 = cp[t + 13 * TILE];
        q6 = cp[t + 14 * TILE]; q7 = cp[t + 15 * TILE];
        SBAR();
        fquad(q0, accA, accB); fquad(q1, accA, accB);
        fquad(q2, accA, accB); fquad(q3, accA, accB);
        fquad(q4, accA, accB); fquad(q5, accA, accB);
        fquad(q6, accA, accB); fquad(q7, accA, accB);
        // issue G2 (4)
        q0 = cp[t + 16 * TILE]; q1 = cp[t + 17 * TILE];
        q2 = cp[t + 18 * TILE]; q3 = cp[t + 19 * TILE];
        SBAR();
        fquad(q0, accA, accB); fquad(q1, accA, accB);
        fquad(q2, accA, accB); fquad(q3, accA, accB);
    } else {
        const int nquad = nA * QPA;
        for (int k = t; k < nquad; k += TILE) fquad(cp[k], accA, accB);
    }

    // --- Phase C: rare ignore anchors subtract their own row (L1/L2-hot).
    float g0 = 0.0f, g1 = 0.0f;
    if (ign) {
        const float4* rp = cp + t * QPA;
        #pragma unroll
        for (int j = 0; j < QPA; ++j) fquad(rp[j], g0, g1);
    }
    float cls_part = 0.75f * (accA + accB - g0 - g1) + cls_corr;

    // Block reduction: wave shuffle then cross-wave via LDS.
    for (int off = 32; off > 0; off >>= 1) {
        cls_part  += __shfl_down(cls_part,  off, 64);
        reg_part  += __shfl_down(reg_part,  off, 64);
        npos_part += __shfl_down(npos_part, off, 64);
    }
    const int wave = t >> 6;
    const int lane = t & 63;
    if (lane == 0) {
        s_red[0][wave] = cls_part;
        s_red[1][wave] = reg_part;
        s_red[2][wave] = npos_part;
    }
    __syncthreads();
    if (t == 0) {
        float cs = 0.0f, rs = 0.0f, ns = 0.0f;
        #pragma unroll
        for (int wv = 0; wv < 4; ++wv) {
            cs += s_red[0][wv];
            rs += s_red[1][wv];
            ns += s_red[2][wv];
        }
        atomicAdd(&ws[b],      cs);
        atomicAdd(&ws[8 + b],  rs);
        atomicAdd(&ws[16 + b], ns);
    }
}

__global__ void finalize_kernel(const float* __restrict__ ws,
                                const float* __restrict__ ann,
                                float* __restrict__ out)
{
    const int t = threadIdx.x;  // 64 threads, one wave
    float cls_v = 0.0f, reg_v = 0.0f;
    if (t < B) {
        bool has_valid = false;
        for (int m = 0; m < M; ++m)
            has_valid = has_valid || (ann[t * M * 5 + m * 5 + 4] != -1.0f);
        const float npos = ws[16 + t];
        // cls accumulator is in log2 units -> scale by ln(2)
        const float cs = 0.69314718056f * ws[t] / fmaxf(npos, 1.0f);
        cls_v = has_valid ? cs : 0.0f;
        reg_v = (npos > 0.0f) ? (ws[8 + t] / fmaxf(npos * 4.0f, 1.0f)) : 0.0f;
    }
    for (int off = 32; off > 0; off >>= 1) {
        cls_v += __shfl_down(cls_v, off, 64);
        reg_v += __shfl_down(reg_v, off, 64);
    }
    if (t == 0) {
        out[0] = cls_v * (1.0f / (float)B);
        out[1] = reg_v * (1.0f / (float)B);
    }
}

extern "C" void kernel_launch(void* const* d_in, const int* in_sizes, int n_in,
                              void* d_out, int out_size, void* d_ws, size_t ws_size,
                              hipStream_t stream) {
    const float* cls     = (const float*)d_in[0];
    const float* reg     = (const float*)d_in[1];
    const float* anchors = (const float*)d_in[2];
    const float* ann     = (const float*)d_in[3];
    float* out = (float*)d_out;
    float* ws  = (float*)d_ws;

    init_ws_kernel<<<1, 32, 0, stream>>>(ws);
    focal_main_kernel<<<dim3(NTILES, B), TILE, 0, stream>>>(cls, reg, anchors, ann, ws);
    finalize_kernel<<<1, 64, 0, stream>>>(ws, ann, out);
}

// Round 12
// 65.018 us; speedup vs baseline: 1.2157x; 1.2157x over previous
//
#include <hip/hip_runtime.h>
#include <math.h>

// Problem dims (fixed by setup_inputs)
constexpr int B = 8;
constexpr int A = 49104;
constexpr int C = 80;       // classes
constexpr int M = 32;       // max annotations
constexpr int TILE = 256;   // anchors per block == threads per block
constexpr int NTILES = (A + TILE - 1) / TILE;  // 192
constexpr int QPA = C / 4;  // 20 float4 per anchor

#define SBAR() __builtin_amdgcn_sched_barrier(0)

// ws layout (floats): [0..7]=cls_sum (log2 units), [8..15]=reg_sum, [16..23]=npos
__global__ void init_ws_kernel(float* ws) {
    int t = threadIdx.x;
    if (t < 24) ws[t] = 0.0f;
}

// Unweighted focal "else" term: f(p) = p^2 * (-log2(1-p)), med3-clamped.
__device__ __forceinline__ void fquad(const float4 p4, float& a0, float& a1) {
    const float px = __builtin_amdgcn_fmed3f(p4.x, 1e-4f, 1.0f - 1e-4f);
    const float py = __builtin_amdgcn_fmed3f(p4.y, 1e-4f, 1.0f - 1e-4f);
    const float pz = __builtin_amdgcn_fmed3f(p4.z, 1e-4f, 1.0f - 1e-4f);
    const float pw = __builtin_amdgcn_fmed3f(p4.w, 1e-4f, 1.0f - 1e-4f);
    a0 = fmaf(px * px, -__log2f(1.0f - px), a0);
    a1 = fmaf(py * py, -__log2f(1.0f - py), a1);
    a0 = fmaf(pz * pz, -__log2f(1.0f - pz), a0);
    a1 = fmaf(pw * pw, -__log2f(1.0f - pw), a1);
}

// launch_bounds(256, 6): 512/6 = 85-VGPR budget so the 8x float4 batch
// stays in registers (R11: at (256,8)/64-VGPR budget regalloc spilled the
// batch to scratch -> 79 MB/dispatch of spill writes, 90 us). 6 blocks/CU
// matches the grid exactly (1536 blocks / 256 CU), so occupancy is
// unchanged vs R5/R8 -- this isolates the MLP variable.
__global__ __launch_bounds__(TILE, 6) void focal_main_kernel(
    const float* __restrict__ cls,      // (B, A, C)
    const float* __restrict__ reg,      // (B, A, 4)
    const float* __restrict__ anchors,  // (A, 4)  y1,x1,y2,x2
    const float* __restrict__ ann,      // (B, M, 5) x1,y1,x2,y2,label
    float* __restrict__ ws)
{
    __shared__ float s_bx1[M], s_by1[M], s_bx2[M], s_by2[M], s_area[M], s_lab[M];
    __shared__ float s_red[3][4];

    const int t    = threadIdx.x;
    const int tile = blockIdx.x;
    const int b    = blockIdx.y;
    const int base = tile * TILE;
    const int nA   = min(TILE, A - base);

    // Preprocess annotations: invalid boxes become degenerate (zero overlap,
    // +inf area) so the IoU loop needs no validity test.
    if (t < M) {
        const float x1 = ann[(b * M + t) * 5 + 0];
        const float y1 = ann[(b * M + t) * 5 + 1];
        const float x2 = ann[(b * M + t) * 5 + 2];
        const float y2 = ann[(b * M + t) * 5 + 3];
        const float lb = ann[(b * M + t) * 5 + 4];
        const bool v = (lb != -1.0f);
        s_bx1[t]  = v ? x1 :  3e18f;
        s_by1[t]  = v ? y1 :  3e18f;
        s_bx2[t]  = v ? x2 : -3e18f;
        s_by2[t]  = v ? y2 : -3e18f;
        s_area[t] = v ? (x2 - x1) * (y2 - y1) : __builtin_inff();
        s_lab[t]  = lb;
    }

    const float4 an = ((const float4*)anchors)[min(base + t, A - 1)];  // y1,x1,y2,x2
    __syncthreads();

    // --- Issue Phase-B group 0 (8 loads) NOW; sched_barrier pins them here
    // so Phase A's ~600-cycle IoU loop hides their latency.
    const float4* cp = (const float4*)(cls + ((size_t)b * A + base) * C);
    const bool full = (nA == TILE);
    float4 q0, q1, q2, q3, q4, q5, q6, q7;
    if (full) {
        q0 = cp[t + 0 * TILE]; q1 = cp[t + 1 * TILE];
        q2 = cp[t + 2 * TILE]; q3 = cp[t + 3 * TILE];
        q4 = cp[t + 4 * TILE]; q5 = cp[t + 5 * TILE];
        q6 = cp[t + 6 * TILE]; q7 = cp[t + 7 * TILE];
    }
    SBAR();

    // --- Phase A: division-free band classification.
    const float aw  = an.w - an.y;
    const float ah  = an.z - an.x;
    const float aarea = ah * aw;
    float e4 = -1.0f, e5 = -1.0f;   // max_j (inter - thr*ua); <0 => iou_max < thr
    if (t < nA) {
        #pragma unroll
        for (int j = 0; j < M; ++j) {
            float iw = fmaxf(fminf(an.w, s_bx2[j]) - fmaxf(an.y, s_bx1[j]), 0.0f);
            float ih = fmaxf(fminf(an.z, s_by2[j]) - fmaxf(an.x, s_by1[j]), 0.0f);
            const float inter = iw * ih;
            const float ua = aarea + s_area[j] - inter;   // >=256, clamp never binds
            e4 = fmaxf(e4, fmaf(-0.4f, ua, inter));
            e5 = fmaxf(e5, fmaf(-0.5f, ua, inter));
        }
    }
    const bool pos = (t < nA) && (e5 >= 0.0f);
    const bool ign = (t < nA) && (e4 >= 0.0f) && !pos;   // 0.4 <= iou_max < 0.5

    // --- Rare pos re-pass: precise argmax + label correction + smooth-L1.
    float cls_corr = 0.0f, reg_part = 0.0f, npos_part = 0.0f;
    if (pos) {
        npos_part = 1.0f;
        float best = -2.0f; int arg = 0;
        for (int j = 0; j < M; ++j) {
            float iw = fmaxf(fminf(an.w, s_bx2[j]) - fmaxf(an.y, s_bx1[j]), 0.0f);
            float ih = fmaxf(fminf(an.z, s_by2[j]) - fmaxf(an.x, s_by1[j]), 0.0f);
            const float inter = iw * ih;
            const float ua = fmaxf(aarea + s_area[j] - inter, 1e-8f);
            const float iou = inter / ua;                 // invalid j: 0/inf = 0
            if (iou > best) { best = iou; arg = j; }
        }
        const int lab = (int)s_lab[arg];
        const float pl = fminf(fmaxf(cls[((size_t)b * A + base + t) * C + lab], 1e-4f), 1.0f - 1e-4f);
        const float ql = 1.0f - pl;
        cls_corr = -0.25f * ql * ql * __log2f(pl) + 0.75f * pl * pl * __log2f(ql);

        const float4 r = ((const float4*)reg)[(size_t)b * A + base + t];
        const float gx1 = s_bx1[arg], gy1 = s_by1[arg];
        const float gx2 = s_bx2[arg], gy2 = s_by2[arg];
        float gw = gx2 - gx1;
        float gh = gy2 - gy1;
        const float gcx = gx1 + 0.5f * gw;
        const float gcy = gy1 + 0.5f * gh;
        const float acx = an.y + 0.5f * aw;
        const float acy = an.x + 0.5f * ah;
        gw = fmaxf(gw, 1.0f);
        gh = fmaxf(gh, 1.0f);
        const float t0 = (gcy - acy) / ah;
        const float t1 = (gcx - acx) / aw;
        const float t2 = __logf(gh / ah);
        const float t3 = __logf(gw / aw);
        const float d0 = fabsf(t0 - r.x);
        const float d1 = fabsf(t1 - r.y);
        const float d2 = fabsf(t2 - r.z);
        const float d3 = fabsf(t3 - r.w);
        const float TH = 1.0f / 9.0f;
        const float SH = 0.5f / 9.0f;
        reg_part = ((d0 <= TH) ? 4.5f * d0 * d0 : d0 - SH)
                 + ((d1 <= TH) ? 4.5f * d1 * d1 : d1 - SH)
                 + ((d2 <= TH) ? 4.5f * d2 * d2 : d2 - SH)
                 + ((d3 <= TH) ? 4.5f * d3 * d3 : d3 - SH);
    }

    // --- Phase B: unconditional focal stream, 8-deep batched loads with
    // sched_barrier fences (issue batch -> fence -> consume).
    float accA = 0.0f, accB = 0.0f;
    if (full) {
        // consume G0 (issued before Phase A)
        fquad(q0, accA, accB); fquad(q1, accA, accB);
        fquad(q2, accA, accB); fquad(q3, accA, accB);
        fquad(q4, accA, accB); fquad(q5, accA, accB);
        fquad(q6, accA, accB); fquad(q7, accA, accB);
        // issue G1
        q0 = cp[t +  8 * TILE]; q1 = cp[t +  9 * TILE];
        q2 = cp[t + 10 * TILE]; q3 = cp[t + 11 * TILE];
        q4 = cp[t + 12 * TILE]; q5 = cp[t + 13 * TILE];
        q6 = cp[t + 14 * TILE]; q7 = cp[t + 15 * TILE];
        SBAR();
        fquad(q0, accA, accB); fquad(q1, accA, accB);
        fquad(q2, accA, accB); fquad(q3, accA, accB);
        fquad(q4, accA, accB); fquad(q5, accA, accB);
        fquad(q6, accA, accB); fquad(q7, accA, accB);
        // issue G2 (4)
        q0 = cp[t + 16 * TILE]; q1 = cp[t + 17 * TILE];
        q2 = cp[t + 18 * TILE]; q3 = cp[t + 19 * TILE];
        SBAR();
        fquad(q0, accA, accB); fquad(q1, accA, accB);
        fquad(q2, accA, accB); fquad(q3, accA, accB);
    } else {
        const int nquad = nA * QPA;
        for (int k = t; k < nquad; k += TILE) fquad(cp[k], accA, accB);
    }

    // --- Phase C: rare ignore anchors subtract their own row (L1/L2-hot).
    float g0 = 0.0f, g1 = 0.0f;
    if (ign) {
        const float4* rp = cp + t * QPA;
        #pragma unroll
        for (int j = 0; j < QPA; ++j) fquad(rp[j], g0, g1);
    }
    float cls_part = 0.75f * (accA + accB - g0 - g1) + cls_corr;

    // Block reduction: wave shuffle then cross-wave via LDS.
    for (int off = 32; off > 0; off >>= 1) {
        cls_part  += __shfl_down(cls_part,  off, 64);
        reg_part  += __shfl_down(reg_part,  off, 64);
        npos_part += __shfl_down(npos_part, off, 64);
    }
    const int wave = t >> 6;
    const int lane = t & 63;
    if (lane == 0) {
        s_red[0][wave] = cls_part;
        s_red[1][wave] = reg_part;
        s_red[2][wave] = npos_part;
    }
    __syncthreads();
    if (t == 0) {
        float cs = 0.0f, rs = 0.0f, ns = 0.0f;
        #pragma unroll
        for (int wv = 0; wv < 4; ++wv) {
            cs += s_red[0][wv];
            rs += s_red[1][wv];
            ns += s_red[2][wv];
        }
        atomicAdd(&ws[b],      cs);
        atomicAdd(&ws[8 + b],  rs);
        atomicAdd(&ws[16 + b], ns);
    }
}

__global__ void finalize_kernel(const float* __restrict__ ws,
                                const float* __restrict__ ann,
                                float* __restrict__ out)
{
    const int t = threadIdx.x;  // 64 threads, one wave
    float cls_v = 0.0f, reg_v = 0.0f;
    if (t < B) {
        bool has_valid = false;
        for (int m = 0; m < M; ++m)
            has_valid = has_valid || (ann[t * M * 5 + m * 5 + 4] != -1.0f);
        const float npos = ws[16 + t];
        // cls accumulator is in log2 units -> scale by ln(2)
        const float cs = 0.69314718056f * ws[t] / fmaxf(npos, 1.0f);
        cls_v = has_valid ? cs : 0.0f;
        reg_v = (npos > 0.0f) ? (ws[8 + t] / fmaxf(npos * 4.0f, 1.0f)) : 0.0f;
    }
    for (int off = 32; off > 0; off >>= 1) {
        cls_v += __shfl_down(cls_v, off, 64);
        reg_v += __shfl_down(reg_v, off, 64);
    }
    if (t == 0) {
        out[0] = cls_v * (1.0f / (float)B);
        out[1] = reg_v * (1.0f / (float)B);
    }
}

extern "C" void kernel_launch(void* const* d_in, const int* in_sizes, int n_in,
                              void* d_out, int out_size, void* d_ws, size_t ws_size,
                              hipStream_t stream) {
    const float* cls     = (const float*)d_in[0];
    const float* reg     = (const float*)d_in[1];
    const float* anchors = (const float*)d_in[2];
    const float* ann     = (const float*)d_in[3];
    float* out = (float*)d_out;
    float* ws  = (float*)d_ws;

    init_ws_kernel<<<1, 32, 0, stream>>>(ws);
    focal_main_kernel<<<dim3(NTILES, B), TILE, 0, stream>>>(cls, reg, anchors, ann, ws);
    finalize_kernel<<<1, 64, 0, stream>>>(ws, ann, out);
}